// Round 1
// baseline (51.394 us; speedup 1.0000x reference)
//
#include <hip/hip_runtime.h>
#include <hip/hip_bf16.h>

// Problem constants (from reference setup_inputs)
#define BB 8
#define LL 4096
#define HH 1024
#define SS 512
#define TT 512

// ---------------------------------------------------------------------------
// Kernel A: per-token dot products with w_src / w_tgt.
// One 64-lane wave per token; 4 waves per 256-thread block.
// outputs: (B*L, H) fp32, read as float4. w: (2H,) fp32.
// ---------------------------------------------------------------------------
__global__ __launch_bounds__(256) void token_dots_kernel(
    const float4* __restrict__ out4,   // (B*L*H/4)
    const float4* __restrict__ w4,     // (2H/4) = 512 float4
    float* __restrict__ dsrc,          // (B*L)
    float* __restrict__ dtgt) {        // (B*L)
  const int token = blockIdx.x * 4 + (threadIdx.x >> 6);
  const int lane = threadIdx.x & 63;
  const int V = HH / 4;  // 256 float4 per token
  size_t tb = (size_t)token * V;
  float as = 0.f, at = 0.f;
#pragma unroll
  for (int j = 0; j < V / 64; ++j) {
    int idx = j * 64 + lane;
    float4 o = out4[tb + idx];
    float4 ws = w4[idx];
    float4 wt = w4[V + idx];
    as += o.x * ws.x + o.y * ws.y + o.z * ws.z + o.w * ws.w;
    at += o.x * wt.x + o.y * wt.y + o.z * wt.z + o.w * wt.w;
  }
#pragma unroll
  for (int off = 32; off >= 1; off >>= 1) {
    as += __shfl_xor(as, off);
    at += __shfl_xor(at, off);
  }
  if (lane == 0) {
    dsrc[token] = as;
    dtgt[token] = at;
  }
}

// ---------------------------------------------------------------------------
// Kernel B: per-batch segment construction (exactly mirrors the reference's
// cumsum / compact / prev_wid / new_seg logic) + segment-mean of the scalars.
// One block per batch, 256 threads, 16 elements/thread.
// ---------------------------------------------------------------------------
__global__ __launch_bounds__(256) void pool_kernel(
    const int* __restrict__ mask_g,    // (B, L)
    const int* __restrict__ wid_g,     // (B, L)
    const float* __restrict__ dsrc,    // (B*L)
    const float* __restrict__ dtgt,    // (B*L)
    float* __restrict__ a_out,         // (B, S)
    float* __restrict__ c_out) {       // (B, T)
  const int b = blockIdx.x;
  const int tid = threadIdx.x;

  __shared__ int s_wid[LL];        // word ids, later reused for new_seg flags
  __shared__ int s_val[LL];        // valid flags
  __shared__ int s_pos[LL];        // inclusive cumsum(valid)-1
  __shared__ int s_compact[LL];    // compacted wids
  __shared__ int s_seg[LL];        // segment index (LL = invalid)
  __shared__ int s_scan[256];
  __shared__ float s_sum[SS + TT + 1];
  __shared__ float s_cnt[SS + TT + 1];

  for (int l = tid; l < LL; l += 256) {
    s_wid[l] = wid_g[b * LL + l];
    s_val[l] = (mask_g[b * LL + l] > 0) ? 1 : 0;
  }
  __syncthreads();

  const int base = tid * 16;

  // ---- scan 1: pos = cumsum(valid) - 1 ----
  int lsum = 0;
#pragma unroll
  for (int k = 0; k < 16; ++k) lsum += s_val[base + k];
  s_scan[tid] = lsum;
  __syncthreads();
#pragma unroll
  for (int off = 1; off < 256; off <<= 1) {
    int v = s_scan[tid];
    int add = (tid >= off) ? s_scan[tid - off] : 0;
    __syncthreads();
    s_scan[tid] = v + add;
    __syncthreads();
  }
  int run = s_scan[tid] - lsum;  // exclusive prefix
#pragma unroll
  for (int k = 0; k < 16; ++k) {
    run += s_val[base + k];
    s_pos[base + k] = run - 1;
  }
  __syncthreads();

  // ---- scatter compact: compact[pos[l]] = wid[l] for valid l ----
#pragma unroll
  for (int k = 0; k < 16; ++k) {
    int l = base + k;
    if (s_val[l]) s_compact[s_pos[l]] = s_wid[l];
  }
  __syncthreads();

  // ---- new_seg = valid & (wid==-1 | prev==-1 | wid!=prev) ----
#pragma unroll
  for (int k = 0; k < 16; ++k) {
    int l = base + k;
    int w = s_wid[l];
    int p = s_pos[l];
    int prev = (p > 0) ? s_compact[p - 1] : -2;
    int ns = (s_val[l] && (w == -1 || prev == -1 || w != prev)) ? 1 : 0;
    s_wid[l] = ns;  // reuse s_wid for new_seg (each thread touches only its own)
  }
  __syncthreads();

  // ---- scan 2: seg = cumsum(new_seg) - 1 (valid only) ----
  lsum = 0;
#pragma unroll
  for (int k = 0; k < 16; ++k) lsum += s_wid[base + k];
  s_scan[tid] = lsum;
  __syncthreads();
#pragma unroll
  for (int off = 1; off < 256; off <<= 1) {
    int v = s_scan[tid];
    int add = (tid >= off) ? s_scan[tid - off] : 0;
    __syncthreads();
    s_scan[tid] = v + add;
    __syncthreads();
  }
  run = s_scan[tid] - lsum;
#pragma unroll
  for (int k = 0; k < 16; ++k) {
    int l = base + k;
    run += s_wid[l];
    s_seg[l] = s_val[l] ? (run - 1) : LL;
  }

  // ---- zero accumulators ----
  for (int i = tid; i < SS + TT + 1; i += 256) {
    s_sum[i] = 0.f;
    s_cnt[i] = 0.f;
  }
  __syncthreads();

  // ---- segment accumulation of the per-token scalars ----
  for (int l = tid; l < LL; l += 256) {
    if (!s_val[l]) continue;
    int sg = s_seg[l];
    if (sg >= 1 && sg <= SS + TT) {
      float v = (sg <= SS) ? dsrc[b * LL + l] : dtgt[b * LL + l];
      atomicAdd(&s_sum[sg], v);
      atomicAdd(&s_cnt[sg], 1.0f);
    }
  }
  __syncthreads();

  // ---- write means ----
  for (int i = tid; i < SS; i += 256)
    a_out[b * SS + i] = s_sum[1 + i] / fmaxf(s_cnt[1 + i], 1.0f);
  for (int i = tid; i < TT; i += 256)
    c_out[b * TT + i] = s_sum[1 + SS + i] / fmaxf(s_cnt[1 + SS + i], 1.0f);
}

// ---------------------------------------------------------------------------
// Kernel C: logits[b,s,t] = a[b,s] + c[b,t] + bias, float4 stores.
// ---------------------------------------------------------------------------
__global__ __launch_bounds__(256) void logits_kernel(
    const float* __restrict__ a,      // (B, S)
    const float4* __restrict__ c4,    // (B, T/4)
    const float* __restrict__ bias_p, // (1,)
    float4* __restrict__ out4) {      // (B*S*T/4)
  int idx = blockIdx.x * 256 + threadIdx.x;   // < B*S*T/4
  int t4 = idx & (TT / 4 - 1);                // 0..127
  int s = (idx >> 7) & (SS - 1);              // 0..511
  int b = idx >> 16;                          // /(128*512)
  float bse = a[b * SS + s] + bias_p[0];
  float4 cv = c4[b * (TT / 4) + t4];
  float4 r;
  r.x = bse + cv.x;
  r.y = bse + cv.y;
  r.z = bse + cv.z;
  r.w = bse + cv.w;
  out4[idx] = r;
}

extern "C" void kernel_launch(void* const* d_in, const int* in_sizes, int n_in,
                              void* d_out, int out_size, void* d_ws, size_t ws_size,
                              hipStream_t stream) {
  const float* outputs = (const float*)d_in[0];       // (B, L, H) fp32
  const int* attention_mask = (const int*)d_in[1];    // (B, L)
  const int* word_ids = (const int*)d_in[2];          // (B, L)
  // d_in[3]=num_src (=512), d_in[4]=num_tgt (=512) — fixed problem constants
  const float* classifier_w = (const float*)d_in[5];  // (2H,)
  const float* classifier_b = (const float*)d_in[6];  // (1,)

  float* ws = (float*)d_ws;
  float* dsrc = ws;                       // B*L
  float* dtgt = ws + BB * LL;             // B*L
  float* a = ws + 2 * BB * LL;            // B*S
  float* c = ws + 2 * BB * LL + BB * SS;  // B*T

  // Kernel A: one wave per token, 4 waves/block.
  const int tokens = BB * LL;
  token_dots_kernel<<<tokens / 4, 256, 0, stream>>>(
      (const float4*)outputs, (const float4*)classifier_w, dsrc, dtgt);

  // Kernel B: one block per batch.
  pool_kernel<<<BB, 256, 0, stream>>>(attention_mask, word_ids, dsrc, dtgt, a, c);

  // Kernel C: broadcast add, float4 stores.
  const int n4 = BB * SS * TT / 4;
  logits_kernel<<<n4 / 256, 256, 0, stream>>>(a, (const float4*)c, classifier_b,
                                              (float4*)d_out);
}

// Round 2
// 38.143 us; speedup vs baseline: 1.3474x; 1.3474x over previous
//
#include <hip/hip_runtime.h>
#include <hip/hip_bf16.h>

// Problem constants (from reference setup_inputs)
#define BB 8
#define LL 4096
#define HH 1024
#define SS 512
#define TT 512
#define NSEG (SS + TT + 1)  // slots 0..1024; we use 1..1024

// ---------------------------------------------------------------------------
// Kernel 1: per-batch segment construction (mirrors reference cumsum/compact/
// prev_wid/new_seg), writes seg ids, per-segment counts, and zeroes sums.
// One block per batch; shfl-based scans (wave scan + 4-element LDS combine).
// ---------------------------------------------------------------------------
__global__ __launch_bounds__(256) void seg_kernel(
    const int* __restrict__ mask_g,   // (B, L)
    const int* __restrict__ wid_g,    // (B, L)
    int* __restrict__ seg_out,        // (B, L)
    float* __restrict__ sums,         // (B, NSEG) -- zeroed here
    float* __restrict__ cnts) {       // (B, NSEG)
  const int b = blockIdx.x;
  const int tid = threadIdx.x;
  const int lane = tid & 63;
  const int wv = tid >> 6;

  __shared__ int s_wid[LL];
  __shared__ int s_val[LL];
  __shared__ int s_pos[LL];
  __shared__ int s_compact[LL];
  __shared__ int s_ns[LL];
  __shared__ int s_wsum[4];
  __shared__ float s_cnt[NSEG];

  for (int l = tid; l < LL; l += 256) {
    s_wid[l] = wid_g[b * LL + l];
    s_val[l] = (mask_g[b * LL + l] > 0) ? 1 : 0;
  }
  for (int i = tid; i < NSEG; i += 256) s_cnt[i] = 0.f;
  __syncthreads();

  const int base = tid * 16;

  // ---- scan 1: pos = cumsum(valid) - 1 ----
  int lsum = 0;
#pragma unroll
  for (int k = 0; k < 16; ++k) lsum += s_val[base + k];
  int x = lsum;
#pragma unroll
  for (int off = 1; off < 64; off <<= 1) {
    int y = __shfl_up(x, off);
    if (lane >= off) x += y;
  }
  if (lane == 63) s_wsum[wv] = x;
  __syncthreads();
  int woff = 0;
  for (int w = 0; w < wv; ++w) woff += s_wsum[w];
  int run = woff + x - lsum;  // exclusive prefix for this thread
#pragma unroll
  for (int k = 0; k < 16; ++k) {
    run += s_val[base + k];
    s_pos[base + k] = run - 1;
  }
  __syncthreads();

  // ---- scatter compact: compact[pos[l]] = wid[l] for valid l ----
#pragma unroll
  for (int k = 0; k < 16; ++k) {
    int l = base + k;
    if (s_val[l]) s_compact[s_pos[l]] = s_wid[l];
  }
  __syncthreads();

  // ---- new_seg ----
#pragma unroll
  for (int k = 0; k < 16; ++k) {
    int l = base + k;
    int w = s_wid[l];
    int p = s_pos[l];
    int prev = (p > 0) ? s_compact[p - 1] : -2;
    s_ns[l] = (s_val[l] && (w == -1 || prev == -1 || w != prev)) ? 1 : 0;
  }
  __syncthreads();

  // ---- scan 2: seg = cumsum(new_seg) - 1 (valid only) ----
  lsum = 0;
#pragma unroll
  for (int k = 0; k < 16; ++k) lsum += s_ns[base + k];
  x = lsum;
#pragma unroll
  for (int off = 1; off < 64; off <<= 1) {
    int y = __shfl_up(x, off);
    if (lane >= off) x += y;
  }
  if (lane == 63) s_wsum[wv] = x;
  __syncthreads();
  woff = 0;
  for (int w = 0; w < wv; ++w) woff += s_wsum[w];
  run = woff + x - lsum;
#pragma unroll
  for (int k = 0; k < 16; ++k) {
    int l = base + k;
    run += s_ns[l];
    int sg = s_val[l] ? (run - 1) : LL;
    seg_out[b * LL + l] = sg;
    if (sg >= 1 && sg <= SS + TT) atomicAdd(&s_cnt[sg], 1.0f);
  }
  __syncthreads();

  for (int i = tid; i < NSEG; i += 256) {
    cnts[b * NSEG + i] = s_cnt[i];
    sums[b * NSEG + i] = 0.f;
  }
}

// ---------------------------------------------------------------------------
// Kernel 2: per-token single dot product, accumulated into per-(b,seg) sums.
// One 64-lane wave per token; waves whose segment is out of range exit
// before touching `outputs` (skips ~42% of the HBM read).
// ---------------------------------------------------------------------------
__global__ __launch_bounds__(256) void dots_kernel(
    const float4* __restrict__ out4,  // (B*L, H/4)
    const float4* __restrict__ w4,    // (2H/4)
    const int* __restrict__ seg,      // (B*L)
    float* __restrict__ sums) {       // (B, NSEG)
  const int token = blockIdx.x * 4 + (threadIdx.x >> 6);
  const int lane = threadIdx.x & 63;
  const int sg = seg[token];
  if (sg < 1 || sg > SS + TT) return;
  const float4* w = w4 + ((sg > SS) ? (HH / 4) : 0);
  const size_t tb = (size_t)token * (HH / 4);
  float acc = 0.f;
#pragma unroll
  for (int j = 0; j < HH / 4 / 64; ++j) {
    int idx = j * 64 + lane;
    float4 o = out4[tb + idx];
    float4 wvv = w[idx];
    acc += o.x * wvv.x + o.y * wvv.y + o.z * wvv.z + o.w * wvv.w;
  }
#pragma unroll
  for (int off = 32; off >= 1; off >>= 1) acc += __shfl_xor(acc, off);
  if (lane == 0) {
    int b = token >> 12;  // L = 4096
    atomicAdd(&sums[b * NSEG + sg], acc);
  }
}

// ---------------------------------------------------------------------------
// Kernel 3: logits[b,s,t] = mean_src[b,s] + mean_tgt[b,t] + bias.
// Means computed inline (division cost ~0.3 us of VALU, L1/L2-resident data).
// ---------------------------------------------------------------------------
__global__ __launch_bounds__(256) void logits_kernel(
    const float* __restrict__ sums,   // (B, NSEG)
    const float* __restrict__ cnts,   // (B, NSEG)
    const float* __restrict__ bias_p, // (1,)
    float4* __restrict__ out4) {      // (B*S*T/4)
  const int idx = blockIdx.x * 256 + threadIdx.x;
  const int t4 = idx & (TT / 4 - 1);           // 0..127
  const int s = (idx >> 7) & (SS - 1);         // 0..511
  const int b = idx >> 16;
  const float* su = sums + b * NSEG;
  const float* cn = cnts + b * NSEG;
  const float base = su[1 + s] / fmaxf(cn[1 + s], 1.f) + bias_p[0];
  const int t0 = t4 * 4;
  float4 r;
  r.x = base + su[1 + SS + t0 + 0] / fmaxf(cn[1 + SS + t0 + 0], 1.f);
  r.y = base + su[1 + SS + t0 + 1] / fmaxf(cn[1 + SS + t0 + 1], 1.f);
  r.z = base + su[1 + SS + t0 + 2] / fmaxf(cn[1 + SS + t0 + 2], 1.f);
  r.w = base + su[1 + SS + t0 + 3] / fmaxf(cn[1 + SS + t0 + 3], 1.f);
  out4[idx] = r;
}

extern "C" void kernel_launch(void* const* d_in, const int* in_sizes, int n_in,
                              void* d_out, int out_size, void* d_ws, size_t ws_size,
                              hipStream_t stream) {
  const float* outputs = (const float*)d_in[0];       // (B, L, H) fp32
  const int* attention_mask = (const int*)d_in[1];    // (B, L)
  const int* word_ids = (const int*)d_in[2];          // (B, L)
  // d_in[3]=num_src (=512), d_in[4]=num_tgt (=512) — fixed problem constants
  const float* classifier_w = (const float*)d_in[5];  // (2H,)
  const float* classifier_b = (const float*)d_in[6];  // (1,)

  float* ws = (float*)d_ws;
  int* seg = (int*)ws;                         // B*L ints
  float* sums = ws + BB * LL;                  // B*NSEG
  float* cnts = sums + BB * NSEG;              // B*NSEG

  seg_kernel<<<BB, 256, 0, stream>>>(attention_mask, word_ids, seg, sums, cnts);

  const int tokens = BB * LL;
  dots_kernel<<<tokens / 4, 256, 0, stream>>>(
      (const float4*)outputs, (const float4*)classifier_w, seg, sums);

  const int n4 = BB * SS * TT / 4;
  logits_kernel<<<n4 / 256, 256, 0, stream>>>(sums, cnts, classifier_b,
                                              (float4*)d_out);
}

// Round 3
// 28.299 us; speedup vs baseline: 1.8161x; 1.3479x over previous
//
#include <hip/hip_runtime.h>
#include <hip/hip_bf16.h>

// Problem constants (from reference setup_inputs)
#define BB 8
#define LL 4096
#define HH 1024
#define SS 512
#define TT 512
#define NSEG (SS + TT + 1)  // slots 0..1024; we use 1..1024

// ---------------------------------------------------------------------------
// Kernel 1: per-batch segment construction (mirrors reference cumsum/compact/
// prev_wid/new_seg). 1024 threads, 4 elements/thread held in registers.
// Writes seg ids, zeroed sums, and reciprocal counts (so the logits kernel
// does FMA instead of divide).
// ---------------------------------------------------------------------------
__global__ __launch_bounds__(1024) void seg_kernel(
    const int4* __restrict__ mask4,   // (B, L/4)
    const int4* __restrict__ wid4,    // (B, L/4)
    int4* __restrict__ seg_out4,      // (B, L/4)
    float* __restrict__ a_sum,        // (B, S) -- zeroed here
    float* __restrict__ t_sum,        // (B, T) -- zeroed here
    float* __restrict__ a_rcp,        // (B, S)
    float* __restrict__ t_rcp) {      // (B, T)
  const int b = blockIdx.x;
  const int tid = threadIdx.x;
  const int lane = tid & 63;
  const int wv = tid >> 6;  // 0..15

  __shared__ int s_compact[LL];
  __shared__ float s_cnt[NSEG];
  __shared__ int s_wsum[16];
  __shared__ int s_wsum2[16];

  const int4 m4 = mask4[b * (LL / 4) + tid];
  const int4 w4 = wid4[b * (LL / 4) + tid];
  const int v0 = m4.x > 0, v1 = m4.y > 0, v2 = m4.z > 0, v3 = m4.w > 0;

  if (tid < NSEG) s_cnt[tid] = 0.f;
  if (tid == 0) s_cnt[1024] = 0.f;

  // ---- scan 1: pos = cumsum(valid) - 1 ----
  const int lsum = v0 + v1 + v2 + v3;
  int x = lsum;
#pragma unroll
  for (int off = 1; off < 64; off <<= 1) {
    int y = __shfl_up(x, off);
    if (lane >= off) x += y;
  }
  if (lane == 63) s_wsum[wv] = x;
  __syncthreads();
  int woff = 0;
#pragma unroll
  for (int w = 0; w < 16; ++w)
    if (w < wv) woff += s_wsum[w];
  int r = woff + x - lsum;  // exclusive prefix
  const int p0 = (r += v0) - 1;
  const int p1 = (r += v1) - 1;
  const int p2 = (r += v2) - 1;
  const int p3 = (r += v3) - 1;

  // ---- scatter compact ----
  if (v0) s_compact[p0] = w4.x;
  if (v1) s_compact[p1] = w4.y;
  if (v2) s_compact[p2] = w4.z;
  if (v3) s_compact[p3] = w4.w;
  __syncthreads();

  // ---- new_seg flags (prev wid via compact) ----
  const int q0 = (p0 > 0) ? s_compact[p0 - 1] : -2;
  const int q1 = (p1 > 0) ? s_compact[p1 - 1] : -2;
  const int q2 = (p2 > 0) ? s_compact[p2 - 1] : -2;
  const int q3 = (p3 > 0) ? s_compact[p3 - 1] : -2;
  const int n0 = (v0 && (w4.x == -1 || q0 == -1 || w4.x != q0)) ? 1 : 0;
  const int n1 = (v1 && (w4.y == -1 || q1 == -1 || w4.y != q1)) ? 1 : 0;
  const int n2 = (v2 && (w4.z == -1 || q2 == -1 || w4.z != q2)) ? 1 : 0;
  const int n3 = (v3 && (w4.w == -1 || q3 == -1 || w4.w != q3)) ? 1 : 0;

  // ---- scan 2: seg = cumsum(new_seg) - 1 ----
  const int lsum2 = n0 + n1 + n2 + n3;
  x = lsum2;
#pragma unroll
  for (int off = 1; off < 64; off <<= 1) {
    int y = __shfl_up(x, off);
    if (lane >= off) x += y;
  }
  if (lane == 63) s_wsum2[wv] = x;
  __syncthreads();
  woff = 0;
#pragma unroll
  for (int w = 0; w < 16; ++w)
    if (w < wv) woff += s_wsum2[w];
  r = woff + x - lsum2;
  int4 sg;
  sg.x = v0 ? ((r += n0) - 1) : LL;
  sg.y = v1 ? ((r += n1) - 1) : LL;
  sg.z = v2 ? ((r += n2) - 1) : LL;
  sg.w = v3 ? ((r += n3) - 1) : LL;
  if (!v0) r += n0;  // (n==0 when invalid; keep exact semantics anyway)
  seg_out4[b * (LL / 4) + tid] = sg;

  if (sg.x >= 1 && sg.x <= SS + TT) atomicAdd(&s_cnt[sg.x], 1.f);
  if (sg.y >= 1 && sg.y <= SS + TT) atomicAdd(&s_cnt[sg.y], 1.f);
  if (sg.z >= 1 && sg.z <= SS + TT) atomicAdd(&s_cnt[sg.z], 1.f);
  if (sg.w >= 1 && sg.w <= SS + TT) atomicAdd(&s_cnt[sg.w], 1.f);
  __syncthreads();

  // ---- emit zeroed sums + reciprocal counts (1024 slots, 1 per thread) ----
  const float rcp = 1.0f / fmaxf(s_cnt[1 + tid], 1.0f);
  if (tid < SS) {
    a_sum[b * SS + tid] = 0.f;
    a_rcp[b * SS + tid] = rcp;
  } else {
    t_sum[b * TT + (tid - SS)] = 0.f;
    t_rcp[b * TT + (tid - SS)] = rcp;
  }
}

// ---------------------------------------------------------------------------
// Kernel 2: per-token single dot product, accumulated into per-(b,seg) sums.
// One 64-lane wave per token; out-of-range waves exit before touching
// `outputs` (skips ~42% of the HBM read).
// ---------------------------------------------------------------------------
__global__ __launch_bounds__(256) void dots_kernel(
    const float4* __restrict__ out4,  // (B*L, H/4)
    const float4* __restrict__ w4,    // (2H/4)
    const int* __restrict__ seg,      // (B*L)
    float* __restrict__ a_sum,        // (B, S)
    float* __restrict__ t_sum) {      // (B, T)
  const int token = blockIdx.x * 4 + (threadIdx.x >> 6);
  const int lane = threadIdx.x & 63;
  const int sg = seg[token];
  if (sg < 1 || sg > SS + TT) return;
  const float4* w = w4 + ((sg > SS) ? (HH / 4) : 0);
  const size_t tb = (size_t)token * (HH / 4);
  float4 o0 = out4[tb + lane];
  float4 o1 = out4[tb + 64 + lane];
  float4 o2 = out4[tb + 128 + lane];
  float4 o3 = out4[tb + 192 + lane];
  float4 wv0 = w[lane];
  float4 wv1 = w[64 + lane];
  float4 wv2 = w[128 + lane];
  float4 wv3 = w[192 + lane];
  float acc = o0.x * wv0.x + o0.y * wv0.y + o0.z * wv0.z + o0.w * wv0.w;
  acc += o1.x * wv1.x + o1.y * wv1.y + o1.z * wv1.z + o1.w * wv1.w;
  acc += o2.x * wv2.x + o2.y * wv2.y + o2.z * wv2.z + o2.w * wv2.w;
  acc += o3.x * wv3.x + o3.y * wv3.y + o3.z * wv3.z + o3.w * wv3.w;
#pragma unroll
  for (int off = 32; off >= 1; off >>= 1) acc += __shfl_xor(acc, off);
  if (lane == 0) {
    const int b = token >> 12;  // L = 4096
    float* dst = (sg <= SS) ? &a_sum[b * SS + sg - 1]
                            : &t_sum[b * TT + sg - 1 - SS];
    atomicAdd(dst, acc);
  }
}

// ---------------------------------------------------------------------------
// Kernel 3: logits[b,s,t] = a_sum[b,s]*a_rcp[b,s] + t_sum[b,t]*t_rcp[b,t] + bias
// Pure FMA, float4 loads/stores.
// ---------------------------------------------------------------------------
__global__ __launch_bounds__(256) void logits_kernel(
    const float* __restrict__ a_sum,  // (B, S)
    const float* __restrict__ a_rcp,  // (B, S)
    const float4* __restrict__ t_sum4,// (B, T/4)
    const float4* __restrict__ t_rcp4,// (B, T/4)
    const float* __restrict__ bias_p, // (1,)
    float4* __restrict__ out4) {      // (B*S*T/4)
  const int idx = blockIdx.x * 256 + threadIdx.x;
  const int t4 = idx & (TT / 4 - 1);           // 0..127
  const int s = (idx >> 7) & (SS - 1);         // 0..511
  const int b = idx >> 16;
  const float base = fmaf(a_sum[b * SS + s], a_rcp[b * SS + s], bias_p[0]);
  const float4 ts = t_sum4[b * (TT / 4) + t4];
  const float4 tr = t_rcp4[b * (TT / 4) + t4];
  float4 out;
  out.x = fmaf(ts.x, tr.x, base);
  out.y = fmaf(ts.y, tr.y, base);
  out.z = fmaf(ts.z, tr.z, base);
  out.w = fmaf(ts.w, tr.w, base);
  out4[idx] = out;
}

extern "C" void kernel_launch(void* const* d_in, const int* in_sizes, int n_in,
                              void* d_out, int out_size, void* d_ws, size_t ws_size,
                              hipStream_t stream) {
  const float* outputs = (const float*)d_in[0];       // (B, L, H) fp32
  const int* attention_mask = (const int*)d_in[1];    // (B, L)
  const int* word_ids = (const int*)d_in[2];          // (B, L)
  // d_in[3]=num_src (=512), d_in[4]=num_tgt (=512) — fixed problem constants
  const float* classifier_w = (const float*)d_in[5];  // (2H,)
  const float* classifier_b = (const float*)d_in[6];  // (1,)

  float* ws = (float*)d_ws;
  int* seg = (int*)ws;                        // B*L ints
  float* a_sum = ws + BB * LL;                // B*S
  float* t_sum = a_sum + BB * SS;             // B*T
  float* a_rcp = t_sum + BB * TT;             // B*S
  float* t_rcp = a_rcp + BB * SS;             // B*T

  seg_kernel<<<BB, 1024, 0, stream>>>(
      (const int4*)attention_mask, (const int4*)word_ids, (int4*)seg,
      a_sum, t_sum, a_rcp, t_rcp);

  const int tokens = BB * LL;
  dots_kernel<<<tokens / 4, 256, 0, stream>>>(
      (const float4*)outputs, (const float4*)classifier_w, seg, a_sum, t_sum);

  const int n4 = BB * SS * TT / 4;
  logits_kernel<<<n4 / 256, 256, 0, stream>>>(
      a_sum, a_rcp, (const float4*)t_sum, (const float4*)t_rcp, classifier_b,
      (float4*)d_out);
}